// Round 15
// baseline (113.562 us; speedup 1.0000x reference)
//
#include <hip/hip_runtime.h>
#include <math.h>

#define NTOK 96
#define EMBED 128
#define HEADS 4
#define HD 32
#define NROW (NTOK*NTOK)     // 9216
#define YT 16
#define NYT (NTOK/YT)        // 6

typedef __attribute__((ext_vector_type(2))) float f32x2;

#if __has_builtin(__builtin_elementwise_fma)
#define PKFMA(A, B, C) __builtin_elementwise_fma((A), (B), (C))
#else
static __device__ __forceinline__ f32x2 PKFMA(f32x2 a, f32x2 b, f32x2 c) {
  f32x2 r; r.x = fmaf(a.x, b.x, c.x); r.y = fmaf(a.y, b.y, c.y); return r;
}
#endif

static __device__ __forceinline__ f32x2 lo2(const float4 v) {
  f32x2 r; r.x = v.x; r.y = v.y; return r;
}
static __device__ __forceinline__ f32x2 hi2(const float4 v) {
  f32x2 r; r.x = v.z; r.y = v.w; return r;
}

// ---- K1: head-major projection, dual stat layouts ----
// pF[v][h][u][32]; murF[v][h][u]; murE[u][h][v]  = {mu,rstd,Sg2,Sgb}
__global__ __launch_bounds__(128) void k_proj(
    const float* __restrict__ x, const float* __restrict__ W,
    const float* __restrict__ b, const float* __restrict__ ln_g,
    const float* __restrict__ ln_b,
    float* __restrict__ pF, float4* __restrict__ murF,
    float4* __restrict__ murE) {
  const int r0 = blockIdx.x * 4;         // global row = u*96 + v
  const int U  = r0 / NTOK;
  const int v0 = r0 % NTOK;
  const int e  = threadIdx.x;            // 0..127
  __shared__ float xt[EMBED][4];
  #pragma unroll
  for (int k = 0; k < 4; ++k)
    xt[e][k] = x[(size_t)(r0 + k) * EMBED + e];
  __syncthreads();

  const float bias = b[e];
  float a0 = bias, a1 = bias, a2 = bias, a3 = bias;
  #pragma unroll 8
  for (int i = 0; i < EMBED; ++i) {
    const float wv = W[(size_t)i * EMBED + e];
    const float4 c = *(const float4*)&xt[i][0];
    a0 = fmaf(wv, c.x, a0); a1 = fmaf(wv, c.y, a1);
    a2 = fmaf(wv, c.z, a2); a3 = fmaf(wv, c.w, a3);
  }

  const int h = e >> 5;
  const int d = e & 31;
  const float gl = ln_g[d];
  const float bl = ln_b[d];
  const float gl2 = gl * gl;
  const float gvb = gl * bl;
  float accs[4] = {a0, a1, a2, a3};
  #pragma unroll
  for (int k = 0; k < 4; ++k) {
    const float val = accs[k];
    const int v = v0 + k;
    pF[(((size_t)v * HEADS + h) * NTOK + U) * HD + d] = val;
    float s1 = val, s2 = val * val, s3 = gl2 * val, s4 = gvb * val;
    #pragma unroll
    for (int m_ = 1; m_ < 32; m_ <<= 1) {
      s1 += __shfl_xor(s1, m_, 64);
      s2 += __shfl_xor(s2, m_, 64);
      s3 += __shfl_xor(s3, m_, 64);
      s4 += __shfl_xor(s4, m_, 64);
    }
    if (d == 0) {
      const float mu = s1 * (1.f / HD);
      const float var = fmaxf(s2 * (1.f / HD) - mu * mu, 0.f);
      float4 o; o.x = mu; o.y = rsqrtf(var + 1e-5f); o.z = s3; o.w = s4;
      murF[((size_t)v * HEADS + h) * NTOK + U] = o;
      murE[((size_t)U * HEADS + h) * NTOK + v] = o;
    }
  }
}

#define RED_PK(A2, MASK) \
  A2.x += __shfl_xor(A2.x, MASK, 64); A2.y += __shfl_xor(A2.y, MASK, 64);

// ---- K2: attention + product-LN aggregation, one head per block ----
// 2304 blocks, XCD-pinned decode (xcd = bid&7 owns 3 (yt,H) combos).
// 512 threads = (y:16, ds:2, da:16). Packed-fp32 (V_PK_*) inner loop.
__global__ __launch_bounds__(512) void k_attn(
    const float* __restrict__ pF, const float4* __restrict__ murF,
    const float4* __restrict__ murE,
    const float* __restrict__ ln_g, const float* __restrict__ ln_b,
    float* __restrict__ agg) {
  const int bid   = blockIdx.x;
  const int xcd   = bid & 7;
  const int q_    = bid >> 3;            // 0..287
  const int combo = xcd * 3 + q_ / NTOK; // 0..23, pinned per XCD
  const int X     = q_ % NTOK;
  const int y0    = (combo % NYT) * YT;
  const int H     = combo / NYT;

  const int tid = threadIdx.x;
  const int y   = tid >> 5;            // 0..15
  const int ds  = (tid >> 4) & 1;      // d-half
  const int da  = tid & 15;            // a-slice
  const int yy  = y0 + y;
  const int eoff = ds * 16;

  __shared__ float e_sm[NTOK][36];     // 13.5 KB (sole LDS use)

  // stage e-side: e[a] = p(X,a) = pF[a][H][X][.]
  {
    const int g0 = tid;                // 0..511
    const int a = g0 >> 3, qq = g0 & 7;
    *(float4*)&e_sm[a][qq * 4] =
        *(const float4*)&pF[(((size_t)a * HEADS + H) * NTOK + X) * HD + qq * 4];
  }
  if (tid < 256) {
    const int g1 = tid + 512;          // 512..767
    const int a = g1 >> 3, qq = g1 & 7;
    *(float4*)&e_sm[a][qq * 4] =
        *(const float4*)&pF[(((size_t)a * HEADS + H) * NTOK + X) * HD + qq * 4];
  }

  // LN constants: T2=sum g^2, Vb=sum g*b, Wb=sum b^2, Mg2=max g^2
  const float glx = ln_g[tid & 31];
  const float blx = ln_b[tid & 31];
  float T2c = glx * glx, Vbc = glx * blx, Wbc = blx * blx, Mg2 = glx * glx;
  #pragma unroll
  for (int m_ = 1; m_ < 32; m_ <<= 1) {
    T2c += __shfl_xor(T2c, m_, 64);
    Vbc += __shfl_xor(Vbc, m_, 64);
    Wbc += __shfl_xor(Wbc, m_, 64);
    Mg2 = fmaxf(Mg2, __shfl_xor(Mg2, m_, 64));
  }
  // score bound: |sc| <= (64*Mg2 + 2*Wb) / sqrt(32)
  const float SB = (64.f * Mg2 + 2.f * Wbc) * 0.17677669529663687f;

  // g^2 weights for this lane's d-range as packed pairs
  f32x2 g2p0, g2p1, g2p2, g2p3, g2p4, g2p5, g2p6, g2p7;
  {
    const float4 t0 = *(const float4*)&ln_g[eoff];
    const float4 t1 = *(const float4*)&ln_g[eoff + 4];
    const float4 t2 = *(const float4*)&ln_g[eoff + 8];
    const float4 t3 = *(const float4*)&ln_g[eoff + 12];
    g2p0 = lo2(t0) * lo2(t0); g2p1 = hi2(t0) * hi2(t0);
    g2p2 = lo2(t1) * lo2(t1); g2p3 = hi2(t1) * hi2(t1);
    g2p4 = lo2(t2) * lo2(t2); g2p5 = hi2(t2) * hi2(t2);
    g2p6 = lo2(t3) * lo2(t3); g2p7 = hi2(t3) * hi2(t3);
  }
  __syncthreads();

  // dense streams: pF[yy][H][a][.], murF[yy][H][a], murE[X][H][a]
  const float* fbase  = pF + (((size_t)yy * HEADS + H) * NTOK) * HD + eoff;
  const float4* mfb   = murF + ((size_t)yy * HEADS + H) * NTOK;
  const float4* meb   = murE + ((size_t)X * HEADS + H) * NTOK;

  f32x2 acc0 = {0.f,0.f}, acc1 = {0.f,0.f}, acc2 = {0.f,0.f}, acc3 = {0.f,0.f};
  f32x2 acc4 = {0.f,0.f}, acc5 = {0.f,0.f}, acc6 = {0.f,0.f}, acc7 = {0.f,0.f};
  float den = 0.f, cc = 0.f;

  #pragma unroll 2
  for (int ia = 0; ia < 6; ++ia) {
    const int a = ia * 16 + da;
    const float4* fp = (const float4*)(fbase + (size_t)a * HD);
    const float4 f0 = fp[0], f1 = fp[1], f2 = fp[2], f3 = fp[3];
    const float4 mrF = mfb[a];
    const float4 mrE = meb[a];
    const float4 e0 = *(const float4*)&e_sm[a][eoff];
    const float4 e1 = *(const float4*)&e_sm[a][eoff + 4];
    const float4 e2 = *(const float4*)&e_sm[a][eoff + 8];
    const float4 e3 = *(const float4*)&e_sm[a][eoff + 12];

    // packed products + moments
    f32x2 t0 = lo2(e0) * lo2(f0), t1 = hi2(e0) * hi2(f0);
    f32x2 t2 = lo2(e1) * lo2(f1), t3 = hi2(e1) * hi2(f1);
    f32x2 t4 = lo2(e2) * lo2(f2), t5 = hi2(e2) * hi2(f2);
    f32x2 t6 = lo2(e3) * lo2(f3), t7 = hi2(e3) * hi2(f3);

    f32x2 s2 = {0.f,0.f}, m2 = {0.f,0.f}, q2 = {0.f,0.f};
    s2 = PKFMA(g2p0, t0, s2); s2 = PKFMA(g2p1, t1, s2);
    s2 = PKFMA(g2p2, t2, s2); s2 = PKFMA(g2p3, t3, s2);
    s2 = PKFMA(g2p4, t4, s2); s2 = PKFMA(g2p5, t5, s2);
    s2 = PKFMA(g2p6, t6, s2); s2 = PKFMA(g2p7, t7, s2);
    m2 = m2 + t0 + t1 + t2 + t3 + t4 + t5 + t6 + t7;
    q2 = PKFMA(t0, t0, q2); q2 = PKFMA(t1, t1, q2);
    q2 = PKFMA(t2, t2, q2); q2 = PKFMA(t3, t3, q2);
    q2 = PKFMA(t4, t4, q2); q2 = PKFMA(t5, t5, q2);
    q2 = PKFMA(t6, t6, q2); q2 = PKFMA(t7, t7, q2);

    float sraw = s2.x + s2.y;
    float m    = m2.x + m2.y;
    float q    = q2.x + q2.y;

    // combine d-halves (xor ds bit)
    sraw += __shfl_xor(sraw, 16, 64);
    m    += __shfl_xor(m,    16, 64);
    q    += __shfl_xor(q,    16, 64);

    // LN'd score from raw moments
    const float muE = mrE.x, rE = mrE.y, Sg2E = mrE.z, SgbE = mrE.w;
    const float muF = mrF.x, rF = mrF.y, Sg2F = mrF.z, SgbF = mrF.w;
    const float inner = sraw - muF * Sg2E - muE * Sg2F + muE * muF * T2c;
    const float sfull = rE * rF * inner
                      + rE * (SgbE - muE * Vbc)
                      + rF * (SgbF - muF * Vbc) + Wbc;
    const float sc = sfull * 0.17677669529663687f;   // 1/sqrt(32)

    // product-LN stats
    const float mu = m * (1.f / HD);
    const float var = fmaxf(fmaf(-mu, mu, q * (1.f / HD)), 0.f);
    const float r = rsqrtf(var + 1e-5f);

    const float ex = __expf(sc - SB);   // <= 1 by construction
    const float w = ex * r;
    den += ex;
    cc  = fmaf(w, mu, cc);
    f32x2 w2; w2.x = w; w2.y = w;
    acc0 = PKFMA(w2, t0, acc0); acc1 = PKFMA(w2, t1, acc1);
    acc2 = PKFMA(w2, t2, acc2); acc3 = PKFMA(w2, t3, acc3);
    acc4 = PKFMA(w2, t4, acc4); acc5 = PKFMA(w2, t5, acc5);
    acc6 = PKFMA(w2, t6, acc6); acc7 = PKFMA(w2, t7, acc7);
  }

  // cross-a reduction over the 16 da lanes
  #pragma unroll
  for (int mask = 1; mask <= 8; mask <<= 1) {
    den += __shfl_xor(den, mask, 64);
    cc  += __shfl_xor(cc,  mask, 64);
    RED_PK(acc0, mask); RED_PK(acc1, mask);
    RED_PK(acc2, mask); RED_PK(acc3, mask);
    RED_PK(acc4, mask); RED_PK(acc5, mask);
    RED_PK(acc6, mask); RED_PK(acc7, mask);
  }

  if (da == 0) {
    const float4 gq0 = *(const float4*)&ln_g[eoff];
    const float4 gq1 = *(const float4*)&ln_g[eoff + 4];
    const float4 gq2 = *(const float4*)&ln_g[eoff + 8];
    const float4 gq3 = *(const float4*)&ln_g[eoff + 12];
    const float4 bq0 = *(const float4*)&ln_b[eoff];
    const float4 bq1 = *(const float4*)&ln_b[eoff + 4];
    const float4 bq2 = *(const float4*)&ln_b[eoff + 8];
    const float4 bq3 = *(const float4*)&ln_b[eoff + 12];
    const float inv = 1.f / den;
    float4 o0, o1, o2, o3;
    o0.x = fmaf(gq0.x, (acc0.x - cc) * inv, bq0.x);
    o0.y = fmaf(gq0.y, (acc0.y - cc) * inv, bq0.y);
    o0.z = fmaf(gq0.z, (acc1.x - cc) * inv, bq0.z);
    o0.w = fmaf(gq0.w, (acc1.y - cc) * inv, bq0.w);
    o1.x = fmaf(gq1.x, (acc2.x - cc) * inv, bq1.x);
    o1.y = fmaf(gq1.y, (acc2.y - cc) * inv, bq1.y);
    o1.z = fmaf(gq1.z, (acc3.x - cc) * inv, bq1.z);
    o1.w = fmaf(gq1.w, (acc3.y - cc) * inv, bq1.w);
    o2.x = fmaf(gq2.x, (acc4.x - cc) * inv, bq2.x);
    o2.y = fmaf(gq2.y, (acc4.y - cc) * inv, bq2.y);
    o2.z = fmaf(gq2.z, (acc5.x - cc) * inv, bq2.z);
    o2.w = fmaf(gq2.w, (acc5.y - cc) * inv, bq2.w);
    o3.x = fmaf(gq3.x, (acc6.x - cc) * inv, bq3.x);
    o3.y = fmaf(gq3.y, (acc6.y - cc) * inv, bq3.y);
    o3.z = fmaf(gq3.z, (acc7.x - cc) * inv, bq3.z);
    o3.w = fmaf(gq3.w, (acc7.y - cc) * inv, bq3.w);
    float* op = agg + ((size_t)(X * NTOK + yy)) * EMBED + H * HD + eoff;
    *(float4*)&op[0]  = o0;
    *(float4*)&op[4]  = o1;
    *(float4*)&op[8]  = o2;
    *(float4*)&op[12] = o3;
  }
}

// ---- K3: out = LN([x, agg] @ Wf + bf) ----
// 1152 blocks x 256 threads, 8 rows per block
__global__ __launch_bounds__(256) void k_final(
    const float* __restrict__ x, const float* __restrict__ agg,
    const float* __restrict__ Wf, const float* __restrict__ bf,
    const float* __restrict__ g2, const float* __restrict__ b2,
    float* __restrict__ out) {
  const int r0 = blockIdx.x * 8;
  const int tid = threadIdx.x;
  const int e = tid & 127;
  const int rh = tid >> 7;               // rows rh*4 .. rh*4+3
  __shared__ float ct[2 * EMBED][12];    // transposed [x|agg], 12.3 KB
  __shared__ float red_sm[4][4][2];

  #pragma unroll
  for (int i = 0; i < 8; ++i) {
    const int g = tid + i * 256;         // 0..2047
    const int yl = g >> 8, col = g & 255;
    const size_t row = (size_t)(r0 + yl);
    const float v = (col < 128) ? x[row * EMBED + col]
                                : agg[row * EMBED + (col - 128)];
    ct[col][yl] = v;
  }
  __syncthreads();

  const float bias = bf[e];
  float acc4[4] = {bias, bias, bias, bias};
  #pragma unroll 8
  for (int i = 0; i < 2 * EMBED; ++i) {
    const float wv = Wf[(size_t)i * EMBED + e];
    const float4 c0 = *(const float4*)&ct[i][rh * 4];
    acc4[0] = fmaf(wv, c0.x, acc4[0]); acc4[1] = fmaf(wv, c0.y, acc4[1]);
    acc4[2] = fmaf(wv, c0.z, acc4[2]); acc4[3] = fmaf(wv, c0.w, acc4[3]);
  }

  const int wid = tid >> 6;
  #pragma unroll
  for (int k = 0; k < 4; ++k) {
    float s1 = acc4[k], s2 = acc4[k] * acc4[k];
    #pragma unroll
    for (int m_ = 1; m_ < 64; m_ <<= 1) {
      s1 += __shfl_xor(s1, m_, 64);
      s2 += __shfl_xor(s2, m_, 64);
    }
    if ((tid & 63) == 0) { red_sm[wid][k][0] = s1; red_sm[wid][k][1] = s2; }
  }
  __syncthreads();

  const float gg = g2[e], bb = b2[e];
  #pragma unroll
  for (int k = 0; k < 4; ++k) {
    const float S1 = red_sm[wid][k][0] + red_sm[wid ^ 1][k][0];
    const float S2 = red_sm[wid][k][1] + red_sm[wid ^ 1][k][1];
    const float mu = S1 * (1.f / EMBED);
    const float var = fmaxf(S2 * (1.f / EMBED) - mu * mu, 0.f);
    const float rstd = rsqrtf(var + 1e-5f);
    out[(size_t)(r0 + rh * 4 + k) * EMBED + e] = (acc4[k] - mu) * rstd * gg + bb;
  }
}

extern "C" void kernel_launch(void* const* d_in, const int* in_sizes, int n_in,
                              void* d_out, int out_size, void* d_ws, size_t ws_size,
                              hipStream_t stream) {
  const float* x    = (const float*)d_in[0];
  const float* W    = (const float*)d_in[1];
  const float* b    = (const float*)d_in[2];
  const float* ln_g = (const float*)d_in[3];
  const float* ln_b = (const float*)d_in[4];
  const float* Wf   = (const float*)d_in[5];
  const float* bf   = (const float*)d_in[6];
  const float* g2   = (const float*)d_in[7];
  const float* b2   = (const float*)d_in[8];
  float* out = (float*)d_out;

  float*  pF   = (float*)d_ws;                         // NROW*128 floats
  float4* murF = (float4*)(pF + (size_t)NROW * EMBED); // NROW*4 float4
  float4* murE = murF + (size_t)NROW * HEADS;          // NROW*4 float4
  float*  agg  = (float*)(murE + (size_t)NROW * HEADS);

  k_proj<<<NROW / 4, 128, 0, stream>>>(x, W, b, ln_g, ln_b, pF, murF, murE);
  k_attn<<<NTOK * NYT * HEADS, 512, 0, stream>>>(pF, murF, murE, ln_g, ln_b, agg);
  k_final<<<NROW / 8, 256, 0, stream>>>(x, agg, Wf, bf, g2, b2, out);
}